// Round 5
// baseline (445.428 us; speedup 1.0000x reference)
//
#include <hip/hip_runtime.h>
#include <stdint.h>

typedef unsigned int u32;

__device__ __forceinline__ float lrelu(float x){ return x > 0.f ? x : 0.2f*x; }

// ---------------- CSR build ----------------
__global__ void k_hist(const int* __restrict__ dst, int* __restrict__ deg, int E){
  int e = blockIdx.x*blockDim.x + threadIdx.x;
  if (e < E) atomicAdd(&deg[dst[e]], 1);
}

__global__ void k_scan1(const int* __restrict__ deg, int* __restrict__ offs,
                        int* __restrict__ bsum, int n){
  __shared__ int lds[256];
  int t = threadIdx.x;
  int base = blockIdx.x*1024 + t*4;
  int v0 = (base+0<n)?deg[base+0]:0;
  int v1 = (base+1<n)?deg[base+1]:0;
  int v2 = (base+2<n)?deg[base+2]:0;
  int v3 = (base+3<n)?deg[base+3]:0;
  int s = v0+v1+v2+v3;
  lds[t] = s; __syncthreads();
  for (int off=1; off<256; off<<=1){
    int tmp = (t>=off)? lds[t-off] : 0;
    __syncthreads();
    lds[t] += tmp;
    __syncthreads();
  }
  int excl = lds[t] - s;
  if (t==255) bsum[blockIdx.x] = lds[255];
  if (base+0<n) offs[base+0] = excl;
  if (base+1<n) offs[base+1] = excl+v0;
  if (base+2<n) offs[base+2] = excl+v0+v1;
  if (base+3<n) offs[base+3] = excl+v0+v1+v2;
}

__global__ void k_scan2(int* bsum, int nb){
  int lane = threadIdx.x;
  int v = (lane<nb)? bsum[lane] : 0;
  int orig = v;
  for (int off=1; off<64; off<<=1){
    int t = __shfl_up(v, off);
    if (lane >= off) v += t;
  }
  if (lane<nb) bsum[lane] = v - orig;   // exclusive
}

__global__ void k_scan3(int* __restrict__ offs, int* __restrict__ cur,
                        const int* __restrict__ bsum, int n){
  int i = blockIdx.x*blockDim.x + threadIdx.x;
  if (i<n){ int v = offs[i] + bsum[i>>10]; offs[i]=v; cur[i]=v; }
}

__global__ void k_scatter(const int* __restrict__ src, const int* __restrict__ dst,
                          int* __restrict__ cur, int* __restrict__ adj, int E){
  int e = blockIdx.x*blockDim.x + threadIdx.x;
  if (e<E){
    int d = dst[e];
    int p = atomicAdd(&cur[d], 1);
    adj[p] = src[e];
  }
}

// ------- register-tiled GEMM: H = X @ W, FIN=128, W staged in LDS -------
// 256 threads; thread = (ci,rg): 4 cols x 4 rows; per k: 4 uniform b32 + 1 b128 + 16 FMA
template<int FOUT>
__global__ __launch_bounds__(256) void k_gemm_t(const float* __restrict__ X,
                                                const float* __restrict__ W,
                                                float* __restrict__ H, int N){
  constexpr int CG = FOUT/4;     // col groups (32 or 16)
  constexpr int RG = 256/CG;     // row groups (8 or 16)
  constexpr int TR = RG*4;       // tile rows (32 or 64)
  __shared__ float xs[TR*128];
  __shared__ float ws[128*FOUT];
  int t = threadIdx.x;
  long i0 = (long)blockIdx.x * TR;
  // stage X tile (zero-fill past N)
  {
    constexpr int NV = TR*32/256;
    #pragma unroll
    for (int j=0;j<NV;j++){
      int idx = t + 256*j;
      int row = idx >> 5, c4 = idx & 31;
      float4 v = make_float4(0.f,0.f,0.f,0.f);
      if (i0 + row < N) v = *(const float4*)&X[(i0+row)*128 + c4*4];
      *(float4*)&xs[row*128 + c4*4] = v;
    }
  }
  // stage W
  {
    constexpr int NW = 128*FOUT/4/256;
    const float4* Wv = (const float4*)W;
    float4* wd = (float4*)ws;
    #pragma unroll
    for (int j=0;j<NW;j++) wd[t + 256*j] = Wv[t + 256*j];
  }
  __syncthreads();
  int ci = t & (CG-1), rg = t / CG;
  float4 a0 = make_float4(0,0,0,0), a1 = a0, a2 = a0, a3 = a0;
  const float* xrow = &xs[(rg*4)*128];
  #pragma unroll 8
  for (int k=0;k<128;k++){
    float4 w4 = *(const float4*)&ws[k*FOUT + ci*4];
    float x0 = xrow[k];
    float x1 = xrow[128 + k];
    float x2 = xrow[256 + k];
    float x3 = xrow[384 + k];
    a0.x = fmaf(x0, w4.x, a0.x); a0.y = fmaf(x0, w4.y, a0.y);
    a0.z = fmaf(x0, w4.z, a0.z); a0.w = fmaf(x0, w4.w, a0.w);
    a1.x = fmaf(x1, w4.x, a1.x); a1.y = fmaf(x1, w4.y, a1.y);
    a1.z = fmaf(x1, w4.z, a1.z); a1.w = fmaf(x1, w4.w, a1.w);
    a2.x = fmaf(x2, w4.x, a2.x); a2.y = fmaf(x2, w4.y, a2.y);
    a2.z = fmaf(x2, w4.z, a2.z); a2.w = fmaf(x2, w4.w, a2.w);
    a3.x = fmaf(x3, w4.x, a3.x); a3.y = fmaf(x3, w4.y, a3.y);
    a3.z = fmaf(x3, w4.z, a3.z); a3.w = fmaf(x3, w4.w, a3.w);
  }
  long ib = i0 + rg*4;
  if (ib+0 < N) *(float4*)&H[(ib+0)*FOUT + ci*4] = a0;
  if (ib+1 < N) *(float4*)&H[(ib+1)*FOUT + ci*4] = a1;
  if (ib+2 < N) *(float4*)&H[(ib+2)*FOUT + ci*4] = a2;
  if (ib+3 < N) *(float4*)&H[(ib+3)*FOUT + ci*4] = a3;
}

// ---------------- per-row attention halves ----------------
template<int F>
__global__ void k_alpha(const float* __restrict__ H, const float* __restrict__ Asrc,
                        const float* __restrict__ Adst, float* __restrict__ AS,
                        float* __restrict__ AD, int N){
  int lane = threadIdx.x & 63;
  int i = blockIdx.x*4 + (threadIdx.x >> 6);
  if (i >= N) return;
  float as = 0.f, ad = 0.f;
  #pragma unroll
  for (int c = lane; c < F; c += 64){
    float hv = H[(long)i*F + c];
    as = fmaf(hv, Asrc[c], as);
    ad = fmaf(hv, Adst[c], ad);
  }
  #pragma unroll
  for (int off=32; off; off>>=1){
    as += __shfl_xor(as, off);
    ad += __shfl_xor(ad, off);
  }
  if (lane==0){ AS[i]=as; AD[i]=ad; }
}

// ---------------- fused segment softmax + weighted aggregation ----------------
template<int F>
__global__ void k_agg(const float* __restrict__ H, const float* __restrict__ AS,
                      const float* __restrict__ AD, const float* __restrict__ B,
                      const int* __restrict__ offs, const int* __restrict__ deg,
                      const int* __restrict__ adj, float* __restrict__ OUT, int N){
  int lane = threadIdx.x & 63;
  int i = blockIdx.x*4 + (threadIdx.x >> 6);
  if (i >= N) return;
  int start = offs[i], dg = deg[i];
  float ad = AD[i];
  float lr_self = lrelu(AS[i] + ad);
  float m = -1e30f, dacc = 0.f;
  for (int b0=0; b0<dg; b0+=64){
    int k = b0 + lane;
    if (k < dg){
      int s = adj[start+k];
      float lr = lrelu(AS[s] + ad);
      float mn = fmaxf(m, lr);
      dacc = dacc*__expf(m-mn) + __expf(lr-mn);
      m = mn;
    }
  }
  #pragma unroll
  for (int off=32; off; off>>=1){
    float m2 = __shfl_xor(m, off);
    float d2 = __shfl_xor(dacc, off);
    float mn = fmaxf(m, m2);
    dacc = dacc*__expf(m-mn) + d2*__expf(m2-mn);
    m = mn;
  }
  float M = fmaxf(m, lr_self);
  float D = dacc*__expf(m-M) + __expf(lr_self-M);
  float invD = 1.f/D;
  float wself = __expf(lr_self-M)*invD;
  float acc0 = wself * H[(long)i*F + lane];
  float acc1 = 0.f;
  if (F==128) acc1 = wself * H[(long)i*F + 64 + lane];
  for (int b0=0; b0<dg; b0+=64){
    int k = b0 + lane;
    int sreg = 0; float wreg = 0.f;
    if (k < dg){
      sreg = adj[start+k];
      wreg = __expf(lrelu(AS[sreg]+ad) - M)*invD;
    }
    int cnt = min(64, dg-b0);
    int kk = 0;
    for (; kk+4<=cnt; kk+=4){
      int   s0=__shfl(sreg,kk),   s1=__shfl(sreg,kk+1),   s2=__shfl(sreg,kk+2),   s3=__shfl(sreg,kk+3);
      float w0=__shfl(wreg,kk),   w1=__shfl(wreg,kk+1),   w2=__shfl(wreg,kk+2),   w3=__shfl(wreg,kk+3);
      float h0 = H[(long)s0*F+lane];
      float h1 = H[(long)s1*F+lane];
      float h2 = H[(long)s2*F+lane];
      float h3 = H[(long)s3*F+lane];
      acc0 += w0*h0 + w1*h1 + w2*h2 + w3*h3;
      if (F==128){
        float g0 = H[(long)s0*F+64+lane];
        float g1 = H[(long)s1*F+64+lane];
        float g2 = H[(long)s2*F+64+lane];
        float g3 = H[(long)s3*F+64+lane];
        acc1 += w0*g0 + w1*g1 + w2*g2 + w3*g3;
      }
    }
    for (; kk<cnt; kk++){
      int s0=__shfl(sreg,kk); float w0=__shfl(wreg,kk);
      acc0 += w0*H[(long)s0*F+lane];
      if (F==128) acc1 += w0*H[(long)s0*F+64+lane];
    }
  }
  float o0 = fmaxf(acc0 + B[lane], 0.f);
  OUT[(long)i*F+lane] = o0;
  if (F==128){
    float o1 = fmaxf(acc1 + B[64+lane], 0.f);
    OUT[(long)i*F+64+lane] = o1;
  }
}

// -------- fused VAE head, register-tiled, W staged in LDS (reused buffer) --------
// 512 threads, 64-row tile; thread = (ci in [0,32), rg in [0,16)), 4 cols x 4 rows.
__global__ __launch_bounds__(512) void k_head_t(
    const float* __restrict__ H2, const float* __restrict__ EPS,
    const float* __restrict__ Wmu, const float* __restrict__ bmu,
    const float* __restrict__ Wlv, const float* __restrict__ blv,
    const float* __restrict__ Wd1, const float* __restrict__ bd1,
    const float* __restrict__ Wd2, const float* __restrict__ bd2,
    float* __restrict__ out_recon, float* __restrict__ out_mu,
    float* __restrict__ out_lv, int N){
  __shared__ float hs[64*64];    // 16 KB  H2 tile
  __shared__ float zs[64*64];    // 16 KB  z tile (lv staging, then z)
  __shared__ float dsb[64*128];  // 32 KB  d tile
  __shared__ float ws[128*128];  // 64 KB  current-phase weights
  int t = threadIdx.x;
  long i0 = (long)blockIdx.x * 64;
  // stage H2 tile
  #pragma unroll
  for (int j=0;j<2;j++){
    int idx = t + 512*j;
    int row = idx >> 4, c4 = idx & 15;
    float4 v = make_float4(0.f,0.f,0.f,0.f);
    if (i0 + row < N) v = *(const float4*)&H2[(i0+row)*64 + c4*4];
    *(float4*)&hs[row*64 + c4*4] = v;
  }
  // stage ws = [Wmu | Wlv] as [64][128]
  #pragma unroll
  for (int j=0;j<4;j++){
    int q = t + 512*j;
    int k = q >> 5, c4 = q & 31;
    float4 v;
    if (c4 < 16) v = *(const float4*)&Wmu[k*64 + c4*4];
    else         v = *(const float4*)&Wlv[k*64 + (c4-16)*4];
    *(float4*)&ws[k*128 + c4*4] = v;
  }
  __syncthreads();
  int ci = t & 31, rg = t >> 5;
  // ---- phase 1: [mu | lv] = h2 @ [Wmu|Wlv] ----
  float4 a0 = make_float4(0,0,0,0), a1 = a0, a2 = a0, a3 = a0;
  {
    const float* xrow = &hs[(rg*4)*64];
    #pragma unroll 8
    for (int k=0;k<64;k++){
      float4 w4 = *(const float4*)&ws[k*128 + ci*4];
      float x0 = xrow[k], x1 = xrow[64+k], x2 = xrow[128+k], x3 = xrow[192+k];
      a0.x=fmaf(x0,w4.x,a0.x); a0.y=fmaf(x0,w4.y,a0.y); a0.z=fmaf(x0,w4.z,a0.z); a0.w=fmaf(x0,w4.w,a0.w);
      a1.x=fmaf(x1,w4.x,a1.x); a1.y=fmaf(x1,w4.y,a1.y); a1.z=fmaf(x1,w4.z,a1.z); a1.w=fmaf(x1,w4.w,a1.w);
      a2.x=fmaf(x2,w4.x,a2.x); a2.y=fmaf(x2,w4.y,a2.y); a2.z=fmaf(x2,w4.z,a2.z); a2.w=fmaf(x2,w4.w,a2.w);
      a3.x=fmaf(x3,w4.x,a3.x); a3.y=fmaf(x3,w4.y,a3.y); a3.z=fmaf(x3,w4.z,a3.z); a3.w=fmaf(x3,w4.w,a3.w);
    }
  }
  bool is_mu = (ci < 16);
  int cbase = is_mu ? ci*4 : (ci-16)*4;
  if (!is_mu){
    float4 bv = *(const float4*)&blv[cbase];
    float4 acc[4] = {a0,a1,a2,a3};
    #pragma unroll
    for (int r=0;r<4;r++){
      long i = i0 + rg*4 + r;
      float4 lv = make_float4(acc[r].x+bv.x, acc[r].y+bv.y, acc[r].z+bv.z, acc[r].w+bv.w);
      if (i < N) *(float4*)&out_lv[i*64 + cbase] = lv;
      *(float4*)&zs[(rg*4+r)*64 + cbase] = lv;
    }
  }
  __syncthreads();   // B1: lv in zs; all phase-1 ws reads done
  if (is_mu){
    float4 bv = *(const float4*)&bmu[cbase];
    float4 acc[4] = {a0,a1,a2,a3};
    #pragma unroll
    for (int r=0;r<4;r++){
      long i = i0 + rg*4 + r;
      float4 mu = make_float4(acc[r].x+bv.x, acc[r].y+bv.y, acc[r].z+bv.z, acc[r].w+bv.w);
      if (i < N) *(float4*)&out_mu[i*64 + cbase] = mu;
      float4 lv = *(const float4*)&zs[(rg*4+r)*64 + cbase];
      float4 e = make_float4(0.f,0.f,0.f,0.f);
      if (i < N) e = *(const float4*)&EPS[i*64 + cbase];
      float4 z;
      z.x = fmaf(e.x, __expf(0.5f*lv.x), mu.x);
      z.y = fmaf(e.y, __expf(0.5f*lv.y), mu.y);
      z.z = fmaf(e.z, __expf(0.5f*lv.z), mu.z);
      z.w = fmaf(e.w, __expf(0.5f*lv.w), mu.w);
      *(float4*)&zs[(rg*4+r)*64 + cbase] = z;
    }
  }
  // stage ws = Wd1 [64][128]
  {
    const float4* Wv = (const float4*)Wd1;
    float4* wd = (float4*)ws;
    #pragma unroll
    for (int j=0;j<4;j++) wd[t + 512*j] = Wv[t + 512*j];
  }
  __syncthreads();   // B2: z + Wd1 visible
  // ---- phase 2: d = relu(z @ Wd1 + bd1) ----
  a0 = make_float4(0,0,0,0); a1 = a0; a2 = a0; a3 = a0;
  {
    const float* xrow = &zs[(rg*4)*64];
    #pragma unroll 8
    for (int k=0;k<64;k++){
      float4 w4 = *(const float4*)&ws[k*128 + ci*4];
      float x0 = xrow[k], x1 = xrow[64+k], x2 = xrow[128+k], x3 = xrow[192+k];
      a0.x=fmaf(x0,w4.x,a0.x); a0.y=fmaf(x0,w4.y,a0.y); a0.z=fmaf(x0,w4.z,a0.z); a0.w=fmaf(x0,w4.w,a0.w);
      a1.x=fmaf(x1,w4.x,a1.x); a1.y=fmaf(x1,w4.y,a1.y); a1.z=fmaf(x1,w4.z,a1.z); a1.w=fmaf(x1,w4.w,a1.w);
      a2.x=fmaf(x2,w4.x,a2.x); a2.y=fmaf(x2,w4.y,a2.y); a2.z=fmaf(x2,w4.z,a2.z); a2.w=fmaf(x2,w4.w,a2.w);
      a3.x=fmaf(x3,w4.x,a3.x); a3.y=fmaf(x3,w4.y,a3.y); a3.z=fmaf(x3,w4.z,a3.z); a3.w=fmaf(x3,w4.w,a3.w);
    }
  }
  __syncthreads();   // B3: phase-2 ws reads done
  {
    float4 bv = *(const float4*)&bd1[ci*4];
    float4 acc[4] = {a0,a1,a2,a3};
    #pragma unroll
    for (int r=0;r<4;r++){
      float4 d;
      d.x = fmaxf(acc[r].x+bv.x, 0.f); d.y = fmaxf(acc[r].y+bv.y, 0.f);
      d.z = fmaxf(acc[r].z+bv.z, 0.f); d.w = fmaxf(acc[r].w+bv.w, 0.f);
      *(float4*)&dsb[(rg*4+r)*128 + ci*4] = d;
    }
  }
  // stage ws = Wd2 [128][128]
  {
    const float4* Wv = (const float4*)Wd2;
    float4* wd = (float4*)ws;
    #pragma unroll
    for (int j=0;j<8;j++) wd[t + 512*j] = Wv[t + 512*j];
  }
  __syncthreads();   // B4: d + Wd2 visible
  // ---- phase 3: recon = sigmoid(d @ Wd2 + bd2) ----
  a0 = make_float4(0,0,0,0); a1 = a0; a2 = a0; a3 = a0;
  {
    const float* xrow = &dsb[(rg*4)*128];
    #pragma unroll 8
    for (int k=0;k<128;k++){
      float4 w4 = *(const float4*)&ws[k*128 + ci*4];
      float x0 = xrow[k], x1 = xrow[128+k], x2 = xrow[256+k], x3 = xrow[384+k];
      a0.x=fmaf(x0,w4.x,a0.x); a0.y=fmaf(x0,w4.y,a0.y); a0.z=fmaf(x0,w4.z,a0.z); a0.w=fmaf(x0,w4.w,a0.w);
      a1.x=fmaf(x1,w4.x,a1.x); a1.y=fmaf(x1,w4.y,a1.y); a1.z=fmaf(x1,w4.z,a1.z); a1.w=fmaf(x1,w4.w,a1.w);
      a2.x=fmaf(x2,w4.x,a2.x); a2.y=fmaf(x2,w4.y,a2.y); a2.z=fmaf(x2,w4.z,a2.z); a2.w=fmaf(x2,w4.w,a2.w);
      a3.x=fmaf(x3,w4.x,a3.x); a3.y=fmaf(x3,w4.y,a3.y); a3.z=fmaf(x3,w4.z,a3.z); a3.w=fmaf(x3,w4.w,a3.w);
    }
  }
  {
    float4 bv = *(const float4*)&bd2[ci*4];
    float4 acc[4] = {a0,a1,a2,a3};
    #pragma unroll
    for (int r=0;r<4;r++){
      long i = i0 + rg*4 + r;
      if (i < N){
        float4 o;
        o.x = 1.f/(1.f+__expf(-(acc[r].x+bv.x)));
        o.y = 1.f/(1.f+__expf(-(acc[r].y+bv.y)));
        o.z = 1.f/(1.f+__expf(-(acc[r].z+bv.z)));
        o.w = 1.f/(1.f+__expf(-(acc[r].w+bv.w)));
        *(float4*)&out_recon[i*128 + ci*4] = o;
      }
    }
  }
}

extern "C" void kernel_launch(void* const* d_in, const int* in_sizes, int n_in,
                              void* d_out, int out_size, void* d_ws, size_t ws_size,
                              hipStream_t stream){
  const float* x    = (const float*)d_in[0];
  const int*   ei   = (const int*)  d_in[1];
  const float* eps  = (const float*)d_in[2];
  const float* W1   = (const float*)d_in[3];
  const float* as1v = (const float*)d_in[4];
  const float* ad1v = (const float*)d_in[5];
  const float* b1   = (const float*)d_in[6];
  const float* W2   = (const float*)d_in[7];
  const float* as2v = (const float*)d_in[8];
  const float* ad2v = (const float*)d_in[9];
  const float* b2   = (const float*)d_in[10];
  const float* Wmu  = (const float*)d_in[11];
  const float* bmu  = (const float*)d_in[12];
  const float* Wlv  = (const float*)d_in[13];
  const float* blv  = (const float*)d_in[14];
  const float* Wd1  = (const float*)d_in[15];
  const float* bd1  = (const float*)d_in[16];
  const float* Wd2  = (const float*)d_in[17];
  const float* bd2  = (const float*)d_in[18];

  const int N = in_sizes[0] / 128;   // 50000
  const int E = in_sizes[1] / 2;     // 800000
  const int* esrc = ei;
  const int* edst = ei + E;

  char* wp = (char*)d_ws;
  auto alloc = [&](size_t bytes)->char*{
    char* p = wp; wp += (bytes + 255) & ~(size_t)255; return p;
  };
  int*   deg  = (int*)  alloc((size_t)N*4);
  int*   offs = (int*)  alloc((size_t)N*4);
  int*   cur  = (int*)  alloc((size_t)N*4);
  int*   bsum = (int*)  alloc(256*4);
  int*   adj  = (int*)  alloc((size_t)E*4);
  float* h1   = (float*)alloc((size_t)N*128*4);
  float* o1   = (float*)alloc((size_t)N*128*4);
  float* AS1  = (float*)alloc((size_t)N*4);
  float* AD1  = (float*)alloc((size_t)N*4);
  float* AS2  = (float*)alloc((size_t)N*4);
  float* AD2  = (float*)alloc((size_t)N*4);
  float* h2 = h1;                    // alias: h1 dead after k_gemm<64> input read
  float* o2 = h1 + (size_t)N*64;
  (void)ws_size; (void)n_in; (void)out_size;

  float* out_recon = (float*)d_out;
  float* out_mu    = out_recon + (size_t)N*128;
  float* out_lv    = out_mu    + (size_t)N*64;

  hipMemsetAsync(deg, 0, (size_t)N*4, stream);
  int eb = (E + 255)/256;
  int nb = (N + 1023)/1024;
  k_hist   <<<eb, 256, 0, stream>>>(edst, deg, E);
  k_scan1  <<<nb, 256, 0, stream>>>(deg, offs, bsum, N);
  k_scan2  <<<1,   64, 0, stream>>>(bsum, nb);
  k_scan3  <<<(N+255)/256, 256, 0, stream>>>(offs, cur, bsum, N);
  k_scatter<<<eb, 256, 0, stream>>>(esrc, edst, cur, adj, E);

  int wb  = (N+3)/4;          // wave per node, 4 waves/block
  int gb1 = (N+31)/32;        // k_gemm_t<128>: 32-row tiles -> 1563
  int gb2 = (N+63)/64;        // k_gemm_t<64>:  64-row tiles -> 782
  int hb  = (N+63)/64;        // k_head_t: 64-row tiles
  k_gemm_t<128><<<gb1, 256, 0, stream>>>(x, W1, h1, N);
  k_alpha<128> <<<wb, 256, 0, stream>>>(h1, as1v, ad1v, AS1, AD1, N);
  k_agg<128>   <<<wb, 256, 0, stream>>>(h1, AS1, AD1, b1, offs, deg, adj, o1, N);
  k_gemm_t<64> <<<gb2, 256, 0, stream>>>(o1, W2, h2, N);
  k_alpha<64>  <<<wb, 256, 0, stream>>>(h2, as2v, ad2v, AS2, AD2, N);
  k_agg<64>    <<<wb, 256, 0, stream>>>(h2, AS2, AD2, b2, offs, deg, adj, o2, N);
  k_head_t     <<<hb, 512, 0, stream>>>(o2, eps, Wmu, bmu, Wlv, blv, Wd1, bd1, Wd2, bd2,
                                        out_recon, out_mu, out_lv, N);
}

// Round 6
// 423.355 us; speedup vs baseline: 1.0521x; 1.0521x over previous
//
#include <hip/hip_runtime.h>
#include <stdint.h>

typedef unsigned int u32;

__device__ __forceinline__ float lrelu(float x){ return x > 0.f ? x : 0.2f*x; }

// ---------------- CSR build ----------------
__global__ void k_hist(const int* __restrict__ dst, int* __restrict__ deg, int E){
  int e = blockIdx.x*blockDim.x + threadIdx.x;
  if (e < E) atomicAdd(&deg[dst[e]], 1);
}

__global__ void k_scan1(const int* __restrict__ deg, int* __restrict__ offs,
                        int* __restrict__ bsum, int n){
  __shared__ int lds[256];
  int t = threadIdx.x;
  int base = blockIdx.x*1024 + t*4;
  int v0 = (base+0<n)?deg[base+0]:0;
  int v1 = (base+1<n)?deg[base+1]:0;
  int v2 = (base+2<n)?deg[base+2]:0;
  int v3 = (base+3<n)?deg[base+3]:0;
  int s = v0+v1+v2+v3;
  lds[t] = s; __syncthreads();
  for (int off=1; off<256; off<<=1){
    int tmp = (t>=off)? lds[t-off] : 0;
    __syncthreads();
    lds[t] += tmp;
    __syncthreads();
  }
  int excl = lds[t] - s;
  if (t==255) bsum[blockIdx.x] = lds[255];
  if (base+0<n) offs[base+0] = excl;
  if (base+1<n) offs[base+1] = excl+v0;
  if (base+2<n) offs[base+2] = excl+v0+v1;
  if (base+3<n) offs[base+3] = excl+v0+v1+v2;
}

__global__ void k_scan2(int* bsum, int nb){
  int lane = threadIdx.x;
  int v = (lane<nb)? bsum[lane] : 0;
  int orig = v;
  for (int off=1; off<64; off<<=1){
    int t = __shfl_up(v, off);
    if (lane >= off) v += t;
  }
  if (lane<nb) bsum[lane] = v - orig;   // exclusive
}

__global__ void k_scan3(int* __restrict__ offs, int* __restrict__ cur,
                        const int* __restrict__ bsum, int n){
  int i = blockIdx.x*blockDim.x + threadIdx.x;
  if (i<n){ int v = offs[i] + bsum[i>>10]; offs[i]=v; cur[i]=v; }
}

__global__ void k_scatter(const int* __restrict__ src, const int* __restrict__ dst,
                          int* __restrict__ cur, int* __restrict__ adj, int E){
  int e = blockIdx.x*blockDim.x + threadIdx.x;
  if (e<E){
    int d = dst[e];
    int p = atomicAdd(&cur[d], 1);
    adj[p] = src[e];
  }
}

// ---- register-tiled GEMM + fused alpha: H = X@W; AS=H.a_src; AD=H.a_dst ----
// 256 threads; W read from global (L1/L2-resident, coalesced 512B/wave/k).
// thread = (ci in [0,CG), rg): 4 cols x RPT rows. LDS = X tile only (32 KB).
template<int FOUT, int RPT>
__global__ __launch_bounds__(256) void k_gemm2(const float* __restrict__ X,
    const float* __restrict__ W, const float* __restrict__ Avs,
    const float* __restrict__ Avd, float* __restrict__ H,
    float* __restrict__ AS, float* __restrict__ AD, int N){
  constexpr int CG = FOUT/4;       // 32 (F=128) or 16 (F=64)
  constexpr int RG = 256/CG;       // 8 or 16
  constexpr int TR = RG*RPT;       // 64 rows
  __shared__ float xs[TR*128];
  int t = threadIdx.x;
  long i0 = (long)blockIdx.x * TR;
  #pragma unroll
  for (int j=0;j<TR*128/4/256;j++){
    int idx = t + 256*j;
    int row = idx >> 5, c4 = idx & 31;
    float4 v = make_float4(0.f,0.f,0.f,0.f);
    if (i0 + row < N) v = *(const float4*)&X[(i0+row)*128 + c4*4];
    *(float4*)&xs[row*128 + c4*4] = v;
  }
  __syncthreads();
  int ci = t & (CG-1), rg = t / CG;
  const float* Wc = W + ci*4;
  float4 acc[RPT];
  #pragma unroll
  for (int r=0;r<RPT;r++) acc[r] = make_float4(0.f,0.f,0.f,0.f);
  const float* xrow = &xs[(rg*RPT)*128];
  #pragma unroll 4
  for (int k=0;k<128;k++){
    float4 w4 = *(const float4*)&Wc[k*FOUT];
    #pragma unroll
    for (int r=0;r<RPT;r++){
      float xv = xrow[r*128 + k];
      acc[r].x = fmaf(xv, w4.x, acc[r].x);
      acc[r].y = fmaf(xv, w4.y, acc[r].y);
      acc[r].z = fmaf(xv, w4.z, acc[r].z);
      acc[r].w = fmaf(xv, w4.w, acc[r].w);
    }
  }
  // fused alpha partials: reduce over the CG contiguous lanes of this rg group
  float4 vs = *(const float4*)&Avs[ci*4];
  float4 vd = *(const float4*)&Avd[ci*4];
  float asv[RPT], adv[RPT];
  #pragma unroll
  for (int r=0;r<RPT;r++){
    asv[r] = acc[r].x*vs.x + acc[r].y*vs.y + acc[r].z*vs.z + acc[r].w*vs.w;
    adv[r] = acc[r].x*vd.x + acc[r].y*vd.y + acc[r].z*vd.z + acc[r].w*vd.w;
  }
  #pragma unroll
  for (int off=1; off<CG; off<<=1){
    #pragma unroll
    for (int r=0;r<RPT;r++){
      asv[r] += __shfl_xor(asv[r], off);
      adv[r] += __shfl_xor(adv[r], off);
    }
  }
  long rb = i0 + rg*RPT;
  #pragma unroll
  for (int r=0;r<RPT;r++)
    if (rb + r < N) *(float4*)&H[(rb+r)*FOUT + ci*4] = acc[r];
  if (ci == 0){
    #pragma unroll
    for (int r=0;r<RPT;r++)
      if (rb + r < N){ AS[rb+r] = asv[r]; AD[rb+r] = adv[r]; }
  }
}

// ---- fused segment softmax + float4 gather aggregation ----
// wave per node; PL=F/4 lanes per edge slice, PARTS=64/PL edges concurrently.
template<int F>
__global__ __launch_bounds__(256) void k_agg2(const float* __restrict__ H,
    const float* __restrict__ AS, const float* __restrict__ AD,
    const float* __restrict__ B, const int* __restrict__ offs,
    const int* __restrict__ deg, const int* __restrict__ adj,
    float* __restrict__ OUT, int N){
  constexpr int PL = F/4;          // 32 (F=128) or 16 (F=64)
  constexpr int PARTS = 64/PL;     // 2 or 4
  int lane = threadIdx.x & 63;
  int i = blockIdx.x*4 + (threadIdx.x >> 6);
  if (i >= N) return;
  int start = offs[i], dg = deg[i];
  float ad = AD[i];
  float lr_self = lrelu(AS[i] + ad);
  int part = lane / PL, lp = lane % PL;
  float M, invD, wfast = 0.f;
  int sfast = i;
  if (dg <= 64){
    // exact softmax, (s, lr) kept in registers — no pass-B re-gather
    float lr = -1e30f;
    if (lane < dg){ sfast = adj[start+lane]; lr = lrelu(AS[sfast] + ad); }
    float m = lr;
    #pragma unroll
    for (int off=32; off; off>>=1) m = fmaxf(m, __shfl_xor(m, off));
    M = fmaxf(m, lr_self);
    float p = (lane < dg) ? __expf(lr - M) : 0.f;
    float d = p;
    #pragma unroll
    for (int off=32; off; off>>=1) d += __shfl_xor(d, off);
    invD = 1.f/(d + __expf(lr_self - M));
    wfast = p * invD;
  } else {
    float m = -1e30f, dacc = 0.f;
    for (int b0=0; b0<dg; b0+=64){
      int k = b0 + lane;
      if (k < dg){
        int s = adj[start+k];
        float lr = lrelu(AS[s] + ad);
        float mn = fmaxf(m, lr);
        dacc = dacc*__expf(m-mn) + __expf(lr-mn);
        m = mn;
      }
    }
    #pragma unroll
    for (int off=32; off; off>>=1){
      float m2 = __shfl_xor(m, off);
      float d2 = __shfl_xor(dacc, off);
      float mn = fmaxf(m, m2);
      dacc = dacc*__expf(m-mn) + d2*__expf(m2-mn);
      m = mn;
    }
    M = fmaxf(m, lr_self);
    invD = 1.f/(dacc*__expf(m-M) + __expf(lr_self-M));
  }
  float4 acc = make_float4(0.f,0.f,0.f,0.f);
  if (part == 0){
    float ws_ = __expf(lr_self - M)*invD;
    float4 hv = *(const float4*)&H[(long)i*F + lp*4];
    acc.x = ws_*hv.x; acc.y = ws_*hv.y; acc.z = ws_*hv.z; acc.w = ws_*hv.w;
  }
  for (int b0=0; b0<dg; b0+=64){
    int s_; float w_;
    if (dg <= 64){ s_ = sfast; w_ = wfast; }
    else {
      s_ = i; w_ = 0.f;
      int k = b0 + lane;
      if (k < dg){ s_ = adj[start+k]; w_ = __expf(lrelu(AS[s_]+ad) - M)*invD; }
    }
    int cnt = min(64, dg - b0);
    for (int kk=0; kk<cnt; kk += PARTS*4){
      #pragma unroll
      for (int j=0;j<4;j++){
        int e = kk + j*PARTS + part;        // e < 64 always; w_=0 pads tail
        int   s = __shfl(s_, e);
        float w = __shfl(w_, e);
        const float4 hv = *(const float4*)&H[(long)s*F + lp*4];
        acc.x = fmaf(w, hv.x, acc.x); acc.y = fmaf(w, hv.y, acc.y);
        acc.z = fmaf(w, hv.z, acc.z); acc.w = fmaf(w, hv.w, acc.w);
      }
    }
  }
  #pragma unroll
  for (int off=PL; off<64; off<<=1){
    acc.x += __shfl_xor(acc.x, off); acc.y += __shfl_xor(acc.y, off);
    acc.z += __shfl_xor(acc.z, off); acc.w += __shfl_xor(acc.w, off);
  }
  if (part == 0){
    float4 bv = *(const float4*)&B[lp*4];
    float4 o;
    o.x = fmaxf(acc.x+bv.x, 0.f); o.y = fmaxf(acc.y+bv.y, 0.f);
    o.z = fmaxf(acc.z+bv.z, 0.f); o.w = fmaxf(acc.w+bv.w, 0.f);
    *(float4*)&OUT[(long)i*F + lp*4] = o;
  }
}

// ---- fused VAE head: 256 thr, 64-row tile, W from global, aliased 32KB LDS ----
__global__ __launch_bounds__(256) void k_head2(
    const float* __restrict__ H2, const float* __restrict__ EPS,
    const float* __restrict__ Wmu, const float* __restrict__ bmu,
    const float* __restrict__ Wlv, const float* __restrict__ blv,
    const float* __restrict__ Wd1, const float* __restrict__ bd1,
    const float* __restrict__ Wd2, const float* __restrict__ bd2,
    float* __restrict__ out_recon, float* __restrict__ out_mu,
    float* __restrict__ out_lv, int N){
  __shared__ float smem[64*128];           // 32 KB
  float* hs  = smem;                       // [64][64] (ph1 input)
  float* zs  = smem + 64*64;               // [64][64] (lv, then z)
  float* dsb = smem;                       // [64][128] aliases hs+zs after ph2
  int t = threadIdx.x;
  long i0 = (long)blockIdx.x * 64;
  #pragma unroll
  for (int j=0;j<4;j++){
    int idx = t + 256*j;
    int row = idx >> 4, c4 = idx & 15;
    float4 v = make_float4(0.f,0.f,0.f,0.f);
    if (i0 + row < N) v = *(const float4*)&H2[(i0+row)*64 + c4*4];
    *(float4*)&hs[row*64 + c4*4] = v;
  }
  __syncthreads();                                           // B0
  int ci = t & 31, rg = t >> 5;
  bool is_mu = (ci < 16);
  int cbase = (is_mu ? ci : ci-16)*4;
  long rb = i0 + rg*8;
  float4 acc[8];
  // ---- phase 1: [mu|lv] = h2 @ [Wmu|Wlv] ----
  #pragma unroll
  for (int r=0;r<8;r++) acc[r] = make_float4(0.f,0.f,0.f,0.f);
  {
    const float* Wp = (is_mu ? Wmu : Wlv) + cbase;
    const float* xrow = &hs[(rg*8)*64];
    #pragma unroll 4
    for (int k=0;k<64;k++){
      float4 w4 = *(const float4*)&Wp[k*64];
      #pragma unroll
      for (int r=0;r<8;r++){
        float xv = xrow[r*64 + k];
        acc[r].x = fmaf(xv,w4.x,acc[r].x); acc[r].y = fmaf(xv,w4.y,acc[r].y);
        acc[r].z = fmaf(xv,w4.z,acc[r].z); acc[r].w = fmaf(xv,w4.w,acc[r].w);
      }
    }
  }
  if (!is_mu){
    float4 bv = *(const float4*)&blv[cbase];
    #pragma unroll
    for (int r=0;r<8;r++){
      float4 lv = make_float4(acc[r].x+bv.x, acc[r].y+bv.y, acc[r].z+bv.z, acc[r].w+bv.w);
      if (rb + r < N) *(float4*)&out_lv[(rb+r)*64 + cbase] = lv;
      *(float4*)&zs[(rg*8+r)*64 + cbase] = lv;
    }
  }
  __syncthreads();                                           // B1: lv visible
  if (is_mu){
    float4 bv = *(const float4*)&bmu[cbase];
    #pragma unroll
    for (int r=0;r<8;r++){
      long i = rb + r;
      float4 mu = make_float4(acc[r].x+bv.x, acc[r].y+bv.y, acc[r].z+bv.z, acc[r].w+bv.w);
      if (i < N) *(float4*)&out_mu[i*64 + cbase] = mu;
      float4 lv = *(const float4*)&zs[(rg*8+r)*64 + cbase];
      float4 e = make_float4(0.f,0.f,0.f,0.f);
      if (i < N) e = *(const float4*)&EPS[i*64 + cbase];
      float4 z;
      z.x = fmaf(e.x, __expf(0.5f*lv.x), mu.x);
      z.y = fmaf(e.y, __expf(0.5f*lv.y), mu.y);
      z.z = fmaf(e.z, __expf(0.5f*lv.z), mu.z);
      z.w = fmaf(e.w, __expf(0.5f*lv.w), mu.w);
      *(float4*)&zs[(rg*8+r)*64 + cbase] = z;
    }
  }
  __syncthreads();                                           // B2: z visible
  // ---- phase 2: d = relu(z @ Wd1 + bd1) ----
  #pragma unroll
  for (int r=0;r<8;r++) acc[r] = make_float4(0.f,0.f,0.f,0.f);
  {
    const float* Wp = Wd1 + ci*4;
    const float* xrow = &zs[(rg*8)*64];
    #pragma unroll 4
    for (int k=0;k<64;k++){
      float4 w4 = *(const float4*)&Wp[k*128];
      #pragma unroll
      for (int r=0;r<8;r++){
        float xv = xrow[r*64 + k];
        acc[r].x = fmaf(xv,w4.x,acc[r].x); acc[r].y = fmaf(xv,w4.y,acc[r].y);
        acc[r].z = fmaf(xv,w4.z,acc[r].z); acc[r].w = fmaf(xv,w4.w,acc[r].w);
      }
    }
  }
  __syncthreads();                      // B3: zs/hs reads done; safe to overwrite
  {
    float4 bv = *(const float4*)&bd1[ci*4];
    #pragma unroll
    for (int r=0;r<8;r++){
      float4 d;
      d.x = fmaxf(acc[r].x+bv.x, 0.f); d.y = fmaxf(acc[r].y+bv.y, 0.f);
      d.z = fmaxf(acc[r].z+bv.z, 0.f); d.w = fmaxf(acc[r].w+bv.w, 0.f);
      *(float4*)&dsb[(rg*8+r)*128 + ci*4] = d;
    }
  }
  __syncthreads();                                           // B4: d visible
  // ---- phase 3: recon = sigmoid(d @ Wd2 + bd2) ----
  #pragma unroll
  for (int r=0;r<8;r++) acc[r] = make_float4(0.f,0.f,0.f,0.f);
  {
    const float* Wp = Wd2 + ci*4;
    const float* xrow = &dsb[(rg*8)*128];
    #pragma unroll 2
    for (int k=0;k<128;k++){
      float4 w4 = *(const float4*)&Wp[k*128];
      #pragma unroll
      for (int r=0;r<8;r++){
        float xv = xrow[r*128 + k];
        acc[r].x = fmaf(xv,w4.x,acc[r].x); acc[r].y = fmaf(xv,w4.y,acc[r].y);
        acc[r].z = fmaf(xv,w4.z,acc[r].z); acc[r].w = fmaf(xv,w4.w,acc[r].w);
      }
    }
  }
  {
    float4 bv = *(const float4*)&bd2[ci*4];
    #pragma unroll
    for (int r=0;r<8;r++){
      long i = rb + r;
      if (i < N){
        float4 o;
        o.x = 1.f/(1.f+__expf(-(acc[r].x+bv.x)));
        o.y = 1.f/(1.f+__expf(-(acc[r].y+bv.y)));
        o.z = 1.f/(1.f+__expf(-(acc[r].z+bv.z)));
        o.w = 1.f/(1.f+__expf(-(acc[r].w+bv.w)));
        *(float4*)&out_recon[i*128 + ci*4] = o;
      }
    }
  }
}

extern "C" void kernel_launch(void* const* d_in, const int* in_sizes, int n_in,
                              void* d_out, int out_size, void* d_ws, size_t ws_size,
                              hipStream_t stream){
  const float* x    = (const float*)d_in[0];
  const int*   ei   = (const int*)  d_in[1];
  const float* eps  = (const float*)d_in[2];
  const float* W1   = (const float*)d_in[3];
  const float* as1v = (const float*)d_in[4];
  const float* ad1v = (const float*)d_in[5];
  const float* b1   = (const float*)d_in[6];
  const float* W2   = (const float*)d_in[7];
  const float* as2v = (const float*)d_in[8];
  const float* ad2v = (const float*)d_in[9];
  const float* b2   = (const float*)d_in[10];
  const float* Wmu  = (const float*)d_in[11];
  const float* bmu  = (const float*)d_in[12];
  const float* Wlv  = (const float*)d_in[13];
  const float* blv  = (const float*)d_in[14];
  const float* Wd1  = (const float*)d_in[15];
  const float* bd1  = (const float*)d_in[16];
  const float* Wd2  = (const float*)d_in[17];
  const float* bd2  = (const float*)d_in[18];

  const int N = in_sizes[0] / 128;   // 50000
  const int E = in_sizes[1] / 2;     // 800000
  const int* esrc = ei;
  const int* edst = ei + E;

  char* wp = (char*)d_ws;
  auto alloc = [&](size_t bytes)->char*{
    char* p = wp; wp += (bytes + 255) & ~(size_t)255; return p;
  };
  int*   deg  = (int*)  alloc((size_t)N*4);
  int*   offs = (int*)  alloc((size_t)N*4);
  int*   cur  = (int*)  alloc((size_t)N*4);
  int*   bsum = (int*)  alloc(256*4);
  int*   adj  = (int*)  alloc((size_t)E*4);
  float* h1   = (float*)alloc((size_t)N*128*4);
  float* o1   = (float*)alloc((size_t)N*128*4);
  float* AS1  = (float*)alloc((size_t)N*4);
  float* AD1  = (float*)alloc((size_t)N*4);
  float* AS2  = (float*)alloc((size_t)N*4);
  float* AD2  = (float*)alloc((size_t)N*4);
  float* h2 = h1;                    // alias: h1 dead before k_gemm2<64> writes
  float* o2 = h1 + (size_t)N*64;
  (void)ws_size; (void)n_in; (void)out_size;

  float* out_recon = (float*)d_out;
  float* out_mu    = out_recon + (size_t)N*128;
  float* out_lv    = out_mu    + (size_t)N*64;

  hipMemsetAsync(deg, 0, (size_t)N*4, stream);
  int eb = (E + 255)/256;
  int nb = (N + 1023)/1024;
  k_hist   <<<eb, 256, 0, stream>>>(edst, deg, E);
  k_scan1  <<<nb, 256, 0, stream>>>(deg, offs, bsum, N);
  k_scan2  <<<1,   64, 0, stream>>>(bsum, nb);
  k_scan3  <<<(N+255)/256, 256, 0, stream>>>(offs, cur, bsum, N);
  k_scatter<<<eb, 256, 0, stream>>>(esrc, edst, cur, adj, E);

  int wb = (N+3)/4;           // wave per node, 4 waves/block
  int gb = (N+63)/64;         // 64-row tiles -> 782 blocks
  k_gemm2<128,8><<<gb, 256, 0, stream>>>(x,  W1, as1v, ad1v, h1, AS1, AD1, N);
  k_agg2<128>   <<<wb, 256, 0, stream>>>(h1, AS1, AD1, b1, offs, deg, adj, o1, N);
  k_gemm2<64,4> <<<gb, 256, 0, stream>>>(o1, W2, as2v, ad2v, h2, AS2, AD2, N);
  k_agg2<64>    <<<wb, 256, 0, stream>>>(h2, AS2, AD2, b2, offs, deg, adj, o2, N);
  k_head2       <<<gb, 256, 0, stream>>>(o2, eps, Wmu, bmu, Wlv, blv, Wd1, bd1, Wd2, bd2,
                                         out_recon, out_mu, out_lv, N);
}

// Round 7
// 420.169 us; speedup vs baseline: 1.0601x; 1.0076x over previous
//
#include <hip/hip_runtime.h>
#include <stdint.h>

typedef unsigned short u16;
typedef unsigned int u32;
typedef short bfrag __attribute__((ext_vector_type(8)));   // 8 bf16 (4 VGPR)
typedef float f32x4 __attribute__((ext_vector_type(4)));

__device__ __forceinline__ u16 f2bf(float f){
  u32 x = __float_as_uint(f);
  return (u16)((x + 0x7FFFu + ((x >> 16) & 1u)) >> 16);   // RNE
}
__device__ __forceinline__ float bf2f(u16 u){ return __uint_as_float(((u32)u)<<16); }
__device__ __forceinline__ void split1(float v, u16* h, u16* l){
  u16 hh = f2bf(v);
  *h = hh;
  *l = f2bf(v - bf2f(hh));
}
__device__ __forceinline__ float lrelu(float x){ return x > 0.f ? x : 0.2f*x; }

// ---------------- CSR build ----------------
__global__ void k_hist(const int* __restrict__ dst, int* __restrict__ deg, int E){
  int e = blockIdx.x*blockDim.x + threadIdx.x;
  if (e < E) atomicAdd(&deg[dst[e]], 1);
}

__global__ void k_scan1(const int* __restrict__ deg, int* __restrict__ offs,
                        int* __restrict__ bsum, int n){
  __shared__ int lds[256];
  int t = threadIdx.x;
  int base = blockIdx.x*1024 + t*4;
  int v0 = (base+0<n)?deg[base+0]:0;
  int v1 = (base+1<n)?deg[base+1]:0;
  int v2 = (base+2<n)?deg[base+2]:0;
  int v3 = (base+3<n)?deg[base+3]:0;
  int s = v0+v1+v2+v3;
  lds[t] = s; __syncthreads();
  for (int off=1; off<256; off<<=1){
    int tmp = (t>=off)? lds[t-off] : 0;
    __syncthreads();
    lds[t] += tmp;
    __syncthreads();
  }
  int excl = lds[t] - s;
  if (t==255) bsum[blockIdx.x] = lds[255];
  if (base+0<n) offs[base+0] = excl;
  if (base+1<n) offs[base+1] = excl+v0;
  if (base+2<n) offs[base+2] = excl+v0+v1;
  if (base+3<n) offs[base+3] = excl+v0+v1+v2;
}

__global__ void k_scan2(int* bsum, int nb){
  int lane = threadIdx.x;
  int v = (lane<nb)? bsum[lane] : 0;
  int orig = v;
  for (int off=1; off<64; off<<=1){
    int t = __shfl_up(v, off);
    if (lane >= off) v += t;
  }
  if (lane<nb) bsum[lane] = v - orig;   // exclusive
}

__global__ void k_scan3(int* __restrict__ offs, int* __restrict__ cur,
                        const int* __restrict__ bsum, int n){
  int i = blockIdx.x*blockDim.x + threadIdx.x;
  if (i<n){ int v = offs[i] + bsum[i>>10]; offs[i]=v; cur[i]=v; }
}

__global__ void k_scatter(const int* __restrict__ src, const int* __restrict__ dst,
                          int* __restrict__ cur, int* __restrict__ adj, int E){
  int e = blockIdx.x*blockDim.x + threadIdx.x;
  if (e<E){
    int d = dst[e];
    int p = atomicAdd(&cur[d], 1);
    adj[p] = src[e];
  }
}

// ---- weight pre-pass: transpose + hi/lo bf16 split, all 5 matrices ----
// layout in wt buffers: [W1t 16384 | W2t 8192 | Wmlt 8192 | Wd1t 8192 | Wd2t 16384]
__global__ void k_cvtw(const float* __restrict__ W1, const float* __restrict__ W2,
                       const float* __restrict__ Wmu, const float* __restrict__ Wlv,
                       const float* __restrict__ Wd1, const float* __restrict__ Wd2,
                       u16* __restrict__ hi, u16* __restrict__ lo){
  int idx = blockIdx.x*256 + threadIdx.x;    // 0..57343
  float v;
  if (idx < 16384){                 // W1t[128][128] = W1[k][c]
    int c = idx >> 7, k = idx & 127; v = W1[k*128 + c];
  } else if (idx < 24576){          // W2t[64][128] = W2[k][c]
    int q = idx - 16384; int c = q >> 7, k = q & 127; v = W2[k*64 + c];
  } else if (idx < 32768){          // Wmlt[128][64]: c<64 mu, else lv
    int q = idx - 24576; int c = q >> 6, k = q & 63;
    v = (c < 64) ? Wmu[k*64 + c] : Wlv[k*64 + (c-64)];
  } else if (idx < 40960){          // Wd1t[128][64] = Wd1[k][c]
    int q = idx - 32768; int c = q >> 6, k = q & 63; v = Wd1[k*128 + c];
  } else {                          // Wd2t[128][128] = Wd2[k][c]
    int q = idx - 40960; int c = q >> 7, k = q & 127; v = Wd2[k*128 + c];
  }
  u16 h, l; split1(v, &h, &l);
  hi[idx] = h; lo[idx] = l;
}

// ---- MFMA GEMM (3-term bf16 split): H(bf16) = X(f32) @ W; fused alpha ----
// 256 thr = 4 waves x 16-row stripes; 64-row tile; FIN=128.
// A from XOR-swizzled LDS (hi/lo); B from pre-transposed global Wt[col][k].
template<int FOUT>
__global__ __launch_bounds__(256) void k_gemm_m(const float* __restrict__ X,
    const u16* __restrict__ Bt_hi, const u16* __restrict__ Bt_lo,
    const float* __restrict__ Avs, const float* __restrict__ Avd,
    u16* __restrict__ H, float* __restrict__ AS, float* __restrict__ AD, int N){
  constexpr int CT = FOUT/16;
  __shared__ __align__(16) u16 xs_hi[64*128];
  __shared__ __align__(16) u16 xs_lo[64*128];
  int t = threadIdx.x;
  long i0 = (long)blockIdx.x * 64;
  #pragma unroll
  for (int j=0;j<8;j++){
    int idx = t + 256*j;               // 2048 groups of 4 cols
    int row = idx >> 5, c4 = idx & 31;
    float4 v = make_float4(0.f,0.f,0.f,0.f);
    if (i0 + row < N) v = *(const float4*)&X[(i0+row)*128 + c4*4];
    u16 h0,h1,h2,h3,l0,l1,l2,l3;
    split1(v.x,&h0,&l0); split1(v.y,&h1,&l1); split1(v.z,&h2,&l2); split1(v.w,&h3,&l3);
    int off = row*128 + (((c4>>1) ^ (row&7))<<3) + (c4&1)*4;   // u16 units
    *(uint2*)&xs_hi[off] = make_uint2((u32)h0 | ((u32)h1<<16), (u32)h2 | ((u32)h3<<16));
    *(uint2*)&xs_lo[off] = make_uint2((u32)l0 | ((u32)l1<<16), (u32)l2 | ((u32)l3<<16));
  }
  __syncthreads();
  int lane = t & 63, w = t >> 6;
  int L = lane & 15, sg = lane >> 4;
  int rbase = w*16;
  bfrag a_hi[4], a_lo[4];
  #pragma unroll
  for (int kk=0;kk<4;kk++){
    int row = rbase + L;
    int off = row*128 + (((kk*4+sg) ^ (row&7))<<3);
    a_hi[kk] = *(const bfrag*)&xs_hi[off];
    a_lo[kk] = *(const bfrag*)&xs_lo[off];
  }
  f32x4 acc[CT];
  #pragma unroll
  for (int ct=0;ct<CT;ct++){
    acc[ct] = (f32x4){0.f,0.f,0.f,0.f};
    int col = ct*16 + L;
    #pragma unroll
    for (int kk=0;kk<4;kk++){
      int ka = kk*32 + sg*8;
      bfrag bh = *(const bfrag*)&Bt_hi[col*128 + ka];
      bfrag bl = *(const bfrag*)&Bt_lo[col*128 + ka];
      acc[ct] = __builtin_amdgcn_mfma_f32_16x16x32_bf16(a_hi[kk], bh, acc[ct], 0,0,0);
      acc[ct] = __builtin_amdgcn_mfma_f32_16x16x32_bf16(a_lo[kk], bh, acc[ct], 0,0,0);
      acc[ct] = __builtin_amdgcn_mfma_f32_16x16x32_bf16(a_hi[kk], bl, acc[ct], 0,0,0);
    }
  }
  // fused alpha (f32, exact w.r.t. acc) + bf16 H store
  float asv[4] = {0,0,0,0}, adv[4] = {0,0,0,0};
  #pragma unroll
  for (int ct=0;ct<CT;ct++){
    int col = ct*16 + L;
    float s = Avs[col], d_ = Avd[col];
    #pragma unroll
    for (int r=0;r<4;r++){
      asv[r] = fmaf(acc[ct][r], s, asv[r]);
      adv[r] = fmaf(acc[ct][r], d_, adv[r]);
    }
  }
  #pragma unroll
  for (int off=1; off<16; off<<=1){
    #pragma unroll
    for (int r=0;r<4;r++){
      asv[r] += __shfl_xor(asv[r], off);
      adv[r] += __shfl_xor(adv[r], off);
    }
  }
  #pragma unroll
  for (int ct=0;ct<CT;ct++){
    int col = ct*16 + L;
    #pragma unroll
    for (int r=0;r<4;r++){
      long row = i0 + rbase + sg*4 + r;      // C/D: col=lane&15, row=sg*4+reg
      if (row < N) H[row*FOUT + col] = f2bf(acc[ct][r]);
    }
  }
  if (L == 0){
    #pragma unroll
    for (int r=0;r<4;r++){
      long row = i0 + rbase + sg*4 + r;
      if (row < N){ AS[row] = asv[r]; AD[row] = adv[r]; }
    }
  }
}

// ---- fused segment softmax + bf16 float4-gather aggregation (f32 out) ----
__device__ __forceinline__ void fma8(float w, int4 hv, float* acc){
  u32 u0=(u32)hv.x, u1=(u32)hv.y, u2=(u32)hv.z, u3=(u32)hv.w;
  acc[0] = fmaf(w, __uint_as_float(u0<<16), acc[0]);
  acc[1] = fmaf(w, __uint_as_float(u0 & 0xffff0000u), acc[1]);
  acc[2] = fmaf(w, __uint_as_float(u1<<16), acc[2]);
  acc[3] = fmaf(w, __uint_as_float(u1 & 0xffff0000u), acc[3]);
  acc[4] = fmaf(w, __uint_as_float(u2<<16), acc[4]);
  acc[5] = fmaf(w, __uint_as_float(u2 & 0xffff0000u), acc[5]);
  acc[6] = fmaf(w, __uint_as_float(u3<<16), acc[6]);
  acc[7] = fmaf(w, __uint_as_float(u3 & 0xffff0000u), acc[7]);
}

template<int F>
__global__ __launch_bounds__(256) void k_agg2b(const u16* __restrict__ H,
    const float* __restrict__ AS, const float* __restrict__ AD,
    const float* __restrict__ B, const int* __restrict__ offs,
    const int* __restrict__ deg, const int* __restrict__ adj,
    float* __restrict__ OUT, int N){
  constexpr int PL = F/8;          // lanes per row slice (16B = 8 bf16)
  constexpr int PARTS = 64/PL;     // edges processed concurrently
  int lane = threadIdx.x & 63;
  int i = blockIdx.x*4 + (threadIdx.x >> 6);
  if (i >= N) return;
  int start = offs[i], dg = deg[i];
  float ad = AD[i];
  float lr_self = lrelu(AS[i] + ad);
  int part = lane / PL, lp = lane % PL;
  float M, invD, wfast = 0.f;
  int sfast = i;
  if (dg <= 64){
    float lr = -1e30f;
    if (lane < dg){ sfast = adj[start+lane]; lr = lrelu(AS[sfast] + ad); }
    float m = lr;
    #pragma unroll
    for (int off=32; off; off>>=1) m = fmaxf(m, __shfl_xor(m, off));
    M = fmaxf(m, lr_self);
    float p = (lane < dg) ? __expf(lr - M) : 0.f;
    float d = p;
    #pragma unroll
    for (int off=32; off; off>>=1) d += __shfl_xor(d, off);
    invD = 1.f/(d + __expf(lr_self - M));
    wfast = p * invD;
  } else {
    float m = -1e30f, dacc = 0.f;
    for (int b0=0; b0<dg; b0+=64){
      int k = b0 + lane;
      if (k < dg){
        int s = adj[start+k];
        float lr = lrelu(AS[s] + ad);
        float mn = fmaxf(m, lr);
        dacc = dacc*__expf(m-mn) + __expf(lr-mn);
        m = mn;
      }
    }
    #pragma unroll
    for (int off=32; off; off>>=1){
      float m2 = __shfl_xor(m, off);
      float d2 = __shfl_xor(dacc, off);
      float mn = fmaxf(m, m2);
      dacc = dacc*__expf(m-mn) + d2*__expf(m2-mn);
      m = mn;
    }
    M = fmaxf(m, lr_self);
    invD = 1.f/(dacc*__expf(m-M) + __expf(lr_self-M));
  }
  float acc8[8] = {0,0,0,0,0,0,0,0};
  if (part == 0){
    float ws_ = __expf(lr_self - M)*invD;
    int4 hv = *(const int4*)(H + (long)i*F + lp*8);
    fma8(ws_, hv, acc8);
  }
  for (int b0=0; b0<dg; b0+=64){
    int s_; float w_;
    if (dg <= 64){ s_ = sfast; w_ = wfast; }
    else {
      s_ = i; w_ = 0.f;
      int k = b0 + lane;
      if (k < dg){ s_ = adj[start+k]; w_ = __expf(lrelu(AS[s_]+ad) - M)*invD; }
    }
    int cnt = min(64, dg - b0);
    for (int kk=0; kk<cnt; kk += PARTS*4){
      #pragma unroll
      for (int j=0;j<4;j++){
        int e = kk + j*PARTS + part;           // < 64 always; w_=0 pads
        int   s = __shfl(s_, e);
        float w = __shfl(w_, e);
        int4 hv = *(const int4*)(H + (long)s*F + lp*8);
        fma8(w, hv, acc8);
      }
    }
  }
  #pragma unroll
  for (int off=PL; off<64; off<<=1){
    #pragma unroll
    for (int j=0;j<8;j++) acc8[j] += __shfl_xor(acc8[j], off);
  }
  if (part == 0){
    float4 b0v = *(const float4*)&B[lp*8];
    float4 b1v = *(const float4*)&B[lp*8+4];
    float4 o0, o1;
    o0.x = fmaxf(acc8[0]+b0v.x, 0.f); o0.y = fmaxf(acc8[1]+b0v.y, 0.f);
    o0.z = fmaxf(acc8[2]+b0v.z, 0.f); o0.w = fmaxf(acc8[3]+b0v.w, 0.f);
    o1.x = fmaxf(acc8[4]+b1v.x, 0.f); o1.y = fmaxf(acc8[5]+b1v.y, 0.f);
    o1.z = fmaxf(acc8[6]+b1v.z, 0.f); o1.w = fmaxf(acc8[7]+b1v.w, 0.f);
    *(float4*)&OUT[(long)i*F + lp*8]     = o0;
    *(float4*)&OUT[(long)i*F + lp*8 + 4] = o1;
  }
}

// ---- fused VAE head, MFMA 3-term split, 3 chained phases, 32 KB aliased LDS ----
__global__ __launch_bounds__(256) void k_head_m(
    const float* __restrict__ H2, const float* __restrict__ EPS,
    const u16* __restrict__ Wml_hi, const u16* __restrict__ Wml_lo,
    const float* __restrict__ bmu, const float* __restrict__ blv,
    const u16* __restrict__ Wd1_hi, const u16* __restrict__ Wd1_lo,
    const float* __restrict__ bd1,
    const u16* __restrict__ Wd2_hi, const u16* __restrict__ Wd2_lo,
    const float* __restrict__ bd2,
    float* __restrict__ out_recon, float* __restrict__ out_mu,
    float* __restrict__ out_lv, int N){
  __shared__ __align__(16) u16 smem[16384];   // 32 KB
  u16* hs_hi = smem;              // [64][64]
  u16* hs_lo = smem + 4096;
  u16* zs_hi = smem + 8192;       // [64][64]
  u16* zs_lo = smem + 12288;
  u16* ds_hi = smem;              // [64][128] aliases hs (after barrier)
  u16* ds_lo = smem + 8192;       // [64][128] aliases zs
  int t = threadIdx.x;
  long i0 = (long)blockIdx.x * 64;
  #pragma unroll
  for (int j=0;j<4;j++){
    int idx = t + 256*j;                // 1024 groups of 4 cols
    int row = idx >> 4, c4 = idx & 15;
    float4 v = make_float4(0.f,0.f,0.f,0.f);
    if (i0 + row < N) v = *(const float4*)&H2[(i0+row)*64 + c4*4];
    u16 h0,h1,h2,h3,l0,l1,l2,l3;
    split1(v.x,&h0,&l0); split1(v.y,&h1,&l1); split1(v.z,&h2,&l2); split1(v.w,&h3,&l3);
    int off = row*64 + (((c4>>1) ^ (row&7))<<3) + (c4&1)*4;
    *(uint2*)&hs_hi[off] = make_uint2((u32)h0 | ((u32)h1<<16), (u32)h2 | ((u32)h3<<16));
    *(uint2*)&hs_lo[off] = make_uint2((u32)l0 | ((u32)l1<<16), (u32)l2 | ((u32)l3<<16));
  }
  __syncthreads();                                   // B0
  int lane = t & 63, w = t >> 6, L = lane & 15, sg = lane >> 4;
  int rbase = w*16;
  // ---- phase 1: [mu|lv] = h2 @ Wmlt ----
  f32x4 acc1[8];
  {
    bfrag ah[2], al[2];
    #pragma unroll
    for (int kk=0;kk<2;kk++){
      int row = rbase + L;
      int off = row*64 + (((kk*4+sg) ^ (row&7))<<3);
      ah[kk] = *(const bfrag*)&hs_hi[off];
      al[kk] = *(const bfrag*)&hs_lo[off];
    }
    #pragma unroll
    for (int ct=0;ct<8;ct++){
      acc1[ct] = (f32x4){0.f,0.f,0.f,0.f};
      int col = ct*16 + L;
      #pragma unroll
      for (int kk=0;kk<2;kk++){
        int ka = kk*32 + sg*8;
        bfrag bh = *(const bfrag*)&Wml_hi[col*64 + ka];
        bfrag bl = *(const bfrag*)&Wml_lo[col*64 + ka];
        acc1[ct] = __builtin_amdgcn_mfma_f32_16x16x32_bf16(ah[kk], bh, acc1[ct], 0,0,0);
        acc1[ct] = __builtin_amdgcn_mfma_f32_16x16x32_bf16(al[kk], bh, acc1[ct], 0,0,0);
        acc1[ct] = __builtin_amdgcn_mfma_f32_16x16x32_bf16(ah[kk], bl, acc1[ct], 0,0,0);
      }
    }
  }
  // epilogue 1: mu/lv out (f32), z -> zs (split bf16)
  #pragma unroll
  for (int ct=0;ct<4;ct++){
    int c = ct*16 + L;
    float bm = bmu[c], bl_ = blv[c];
    #pragma unroll
    for (int r=0;r<4;r++){
      int row_l = rbase + sg*4 + r;
      long i = i0 + row_l;
      float mu = acc1[ct][r] + bm;
      float lv = acc1[ct+4][r] + bl_;
      float e = 0.f;
      if (i < N){ out_mu[i*64+c] = mu; out_lv[i*64+c] = lv; e = EPS[i*64+c]; }
      float z = fmaf(e, __expf(0.5f*lv), mu);
      u16 zh, zl; split1(z,&zh,&zl);
      int zo = row_l*64 + ((((c>>3)) ^ (row_l&7))<<3) + (c&7);
      zs_hi[zo] = zh; zs_lo[zo] = zl;
    }
  }
  // ---- phase 2: d = relu(z @ Wd1t + bd1) ----
  f32x4 acc2[8];
  {
    bfrag ah[2], al[2];
    #pragma unroll
    for (int kk=0;kk<2;kk++){
      int row = rbase + L;
      int off = row*64 + (((kk*4+sg) ^ (row&7))<<3);
      ah[kk] = *(const bfrag*)&zs_hi[off];
      al[kk] = *(const bfrag*)&zs_lo[off];
    }
    #pragma unroll
    for (int ct=0;ct<8;ct++){
      acc2[ct] = (f32x4){0.f,0.f,0.f,0.f};
      int col = ct*16 + L;
      #pragma unroll
      for (int kk=0;kk<2;kk++){
        int ka = kk*32 + sg*8;
        bfrag bh = *(const bfrag*)&Wd1_hi[col*64 + ka];
        bfrag bl = *(const bfrag*)&Wd1_lo[col*64 + ka];
        acc2[ct] = __builtin_amdgcn_mfma_f32_16x16x32_bf16(ah[kk], bh, acc2[ct], 0,0,0);
        acc2[ct] = __builtin_amdgcn_mfma_f32_16x16x32_bf16(al[kk], bh, acc2[ct], 0,0,0);
        acc2[ct] = __builtin_amdgcn_mfma_f32_16x16x32_bf16(ah[kk], bl, acc2[ct], 0,0,0);
      }
    }
  }
  __syncthreads();   // B1: all hs/zs reads done -> ds may alias them
  #pragma unroll
  for (int ct=0;ct<8;ct++){
    int c = ct*16 + L;
    float bb = bd1[c];
    #pragma unroll
    for (int r=0;r<4;r++){
      int row_l = rbase + sg*4 + r;
      float d = fmaxf(acc2[ct][r] + bb, 0.f);
      u16 dh, dl; split1(d,&dh,&dl);
      int dof = row_l*128 + ((((c>>3)) ^ (row_l&7))<<3) + (c&7);
      ds_hi[dof] = dh; ds_lo[dof] = dl;
    }
  }
  // ---- phase 3: recon = sigmoid(d @ Wd2t + bd2) ----
  f32x4 acc3[8];
  {
    bfrag ah[4], al[4];
    #pragma unroll
    for (int kk=0;kk<4;kk++){
      int row = rbase + L;
      int off = row*128 + (((kk*4+sg) ^ (row&7))<<3);
      ah[kk] = *(const bfrag*)&ds_hi[off];
      al[kk] = *(const bfrag*)&ds_lo[off];
    }
    #pragma unroll
    for (int ct=0;ct<8;ct++){
      acc3[ct] = (f32x4){0.f,0.f,0.f,0.f};
      int col = ct*16 + L;
      #pragma unroll
      for (int kk=0;kk<4;kk++){
        int ka = kk*32 + sg*8;
        bfrag bh = *(const bfrag*)&Wd2_hi[col*128 + ka];
        bfrag bl = *(const bfrag*)&Wd2_lo[col*128 + ka];
        acc3[ct] = __builtin_amdgcn_mfma_f32_16x16x32_bf16(ah[kk], bh, acc3[ct], 0,0,0);
        acc3[ct] = __builtin_amdgcn_mfma_f32_16x16x32_bf16(al[kk], bh, acc3[ct], 0,0,0);
        acc3[ct] = __builtin_amdgcn_mfma_f32_16x16x32_bf16(ah[kk], bl, acc3[ct], 0,0,0);
      }
    }
  }
  #pragma unroll
  for (int ct=0;ct<8;ct++){
    int c = ct*16 + L;
    float bb = bd2[c];
    #pragma unroll
    for (int r=0;r<4;r++){
      long i = i0 + rbase + sg*4 + r;
      if (i < N)
        out_recon[i*128+c] = 1.f/(1.f+__expf(-(acc3[ct][r] + bb)));
    }
  }
}

extern "C" void kernel_launch(void* const* d_in, const int* in_sizes, int n_in,
                              void* d_out, int out_size, void* d_ws, size_t ws_size,
                              hipStream_t stream){
  const float* x    = (const float*)d_in[0];
  const int*   ei   = (const int*)  d_in[1];
  const float* eps  = (const float*)d_in[2];
  const float* W1   = (const float*)d_in[3];
  const float* as1v = (const float*)d_in[4];
  const float* ad1v = (const float*)d_in[5];
  const float* b1   = (const float*)d_in[6];
  const float* W2   = (const float*)d_in[7];
  const float* as2v = (const float*)d_in[8];
  const float* ad2v = (const float*)d_in[9];
  const float* b2   = (const float*)d_in[10];
  const float* Wmu  = (const float*)d_in[11];
  const float* bmu  = (const float*)d_in[12];
  const float* Wlv  = (const float*)d_in[13];
  const float* blv  = (const float*)d_in[14];
  const float* Wd1  = (const float*)d_in[15];
  const float* bd1  = (const float*)d_in[16];
  const float* Wd2  = (const float*)d_in[17];
  const float* bd2  = (const float*)d_in[18];

  const int N = in_sizes[0] / 128;   // 50000
  const int E = in_sizes[1] / 2;     // 800000
  const int* esrc = ei;
  const int* edst = ei + E;

  char* wp = (char*)d_ws;
  auto alloc = [&](size_t bytes)->char*{
    char* p = wp; wp += (bytes + 255) & ~(size_t)255; return p;
  };
  int*   deg  = (int*)  alloc((size_t)N*4);
  int*   offs = (int*)  alloc((size_t)N*4);
  int*   cur  = (int*)  alloc((size_t)N*4);
  int*   bsum = (int*)  alloc(256*4);
  int*   adj  = (int*)  alloc((size_t)E*4);
  u16*   h1b  = (u16*)  alloc((size_t)N*128*2);   // bf16 H (layer1); layer2 aliases
  float* o1   = (float*)alloc((size_t)N*128*4);   // f32 agg out; o2 aliases
  float* AS1  = (float*)alloc((size_t)N*4);
  float* AD1  = (float*)alloc((size_t)N*4);
  float* AS2  = (float*)alloc((size_t)N*4);
  float* AD2  = (float*)alloc((size_t)N*4);
  u16*   wt_hi = (u16*) alloc(57344*2);
  u16*   wt_lo = (u16*) alloc(57344*2);
  u16*   h2b = h1b;                  // h1b dead after k_agg2b<128>
  float* o2  = o1;                   // o1 dead after k_gemm_m<64> reads it
  (void)ws_size; (void)n_in; (void)out_size;

  const u16 *w1t_hi = wt_hi,        *w1t_lo = wt_lo;
  const u16 *w2t_hi = wt_hi+16384,  *w2t_lo = wt_lo+16384;
  const u16 *wml_hi = wt_hi+24576,  *wml_lo = wt_lo+24576;
  const u16 *wd1t_hi = wt_hi+32768, *wd1t_lo = wt_lo+32768;
  const u16 *wd2t_hi = wt_hi+40960, *wd2t_lo = wt_lo+40960;

  float* out_recon = (float*)d_out;
  float* out_mu    = out_recon + (size_t)N*128;
  float* out_lv    = out_mu    + (size_t)N*64;

  hipMemsetAsync(deg, 0, (size_t)N*4, stream);
  int eb = (E + 255)/256;
  int nb = (N + 1023)/1024;
  k_hist   <<<eb, 256, 0, stream>>>(edst, deg, E);
  k_scan1  <<<nb, 256, 0, stream>>>(deg, offs, bsum, N);
  k_scan2  <<<1,   64, 0, stream>>>(bsum, nb);
  k_scan3  <<<(N+255)/256, 256, 0, stream>>>(offs, cur, bsum, N);
  k_scatter<<<eb, 256, 0, stream>>>(esrc, edst, cur, adj, E);
  k_cvtw   <<<224, 256, 0, stream>>>(W1, W2, Wmu, Wlv, Wd1, Wd2, wt_hi, wt_lo);

  int wb = (N+3)/4;           // wave per node
  int gb = (N+63)/64;         // 64-row tiles -> 782 blocks
  k_gemm_m<128><<<gb, 256, 0, stream>>>(x,  w1t_hi, w1t_lo, as1v, ad1v, h1b, AS1, AD1, N);
  k_agg2b<128> <<<wb, 256, 0, stream>>>(h1b, AS1, AD1, b1, offs, deg, adj, o1, N);
  k_gemm_m<64> <<<gb, 256, 0, stream>>>(o1, w2t_hi, w2t_lo, as2v, ad2v, h2b, AS2, AD2, N);
  k_agg2b<64>  <<<wb, 256, 0, stream>>>(h2b, AS2, AD2, b2, offs, deg, adj, o2, N);
  k_head_m     <<<gb, 256, 0, stream>>>(o2, eps, wml_hi, wml_lo, bmu, blv,
                                        wd1t_hi, wd1t_lo, bd1, wd2t_hi, wd2t_lo, bd2,
                                        out_recon, out_mu, out_lv, N);
}